// Round 5
// baseline (10262.765 us; speedup 1.0000x reference)
//
#include <hip/hip_runtime.h>
#include <stdint.h>

#define NN 4096
#define BB 4
#define RPB 16          // rows per block
#define TPB 1024

// ---------- bf16 round-to-nearest-even ----------
__device__ __forceinline__ uint32_t bf16rne(float f) {
  uint32_t u = __float_as_uint(f);
  return (u + 0x7FFFu + ((u >> 16) & 1u)) >> 16;
}

// ---------- pack B with column permutation ----------
// Storage uint4 index o4 = row*1024 + g*64 + lane holds columns c_u = g*256 + u*64 + lane
// (u = component 0..3). This makes the step kernel's x-tile LDS reads lane-contiguous
// (conflict-free) while keeping B loads 16B-coalesced.
__global__ void pack_perm_kernel(const float* __restrict__ Br, const float* __restrict__ Bi,
                                 uint4* __restrict__ Bp) {
  int o4 = blockIdx.x * blockDim.x + threadIdx.x;    // 0 .. 4096*1024-1
  int lane = o4 & 63;
  int g    = (o4 >> 6) & 15;
  int row  = o4 >> 10;
  size_t base = (size_t)row * NN + g * 256 + lane;
  uint4 o;
  o.x = bf16rne(Br[base +   0]) | (bf16rne(Bi[base +   0]) << 16);
  o.y = bf16rne(Br[base +  64]) | (bf16rne(Bi[base +  64]) << 16);
  o.z = bf16rne(Br[base + 128]) | (bf16rne(Bi[base + 128]) << 16);
  o.w = bf16rne(Br[base + 192]) | (bf16rne(Bi[base + 192]) << 16);
  Bp[o4] = o;
}

// ---------- x0 = exp(i*theta): state (complex interleaved) + out real plane t=0 ----------
__global__ void init_kernel(const float* __restrict__ ang,
                            float2* __restrict__ st0, float* __restrict__ out0) {
  int i = blockIdx.x * blockDim.x + threadIdx.x;
  if (i < BB * NN) {
    float s, c;
    sincosf(ang[i], &s, &c);
    st0[i] = make_float2(c, s);
    out0[i] = c;
  }
}

// ---------- one recurrence step ----------
// state [b][n] complex interleaved (float2); d_out gets REAL part only, [t][b][n]
// LDS: xl[n] = float4{r0,i0,r1,i1}, xh[n] = float4{r2,i2,r3,i3}, red[16][32]
template <bool PACKED>
__global__ __launch_bounds__(TPB)
void step_kernel(const uint4* __restrict__ Bp,
                 const float* __restrict__ Brf,
                 const float* __restrict__ Bif,
                 const float* __restrict__ omega,
                 const float2* __restrict__ stPrev,
                 float2* __restrict__ stNext,
                 float* __restrict__ outRe) {
  extern __shared__ float lds[];
  float* xl  = lds;                // 4096 float4 = 64 KB
  float* xh  = lds + NN * 4;       // 64 KB
  float* red = lds + NN * 8;       // 2 KB

  const int tid = threadIdx.x;

  // ---- stage x_t into LDS: one full b128 per thread-iter, lane-contiguous ----
#pragma unroll
  for (int k = 0; k < 8; ++k) {
    int idx  = tid + k * TPB;            // 0..8191
    int half = idx >> 12;                // 0 -> xl (batches 0,1), 1 -> xh (batches 2,3)
    int n    = idx & (NN - 1);
    float2 v0 = stPrev[(half * 2    ) * NN + n];
    float2 v1 = stPrev[(half * 2 + 1) * NN + n];
    float4 w4 = make_float4(v0.x, v0.y, v1.x, v1.y);
    reinterpret_cast<float4*>(half ? xh : xl)[n] = w4;
  }
  __syncthreads();

  const int w    = tid >> 6;
  const int lane = tid & 63;
  const int rg   = w >> 2;             // row group (4 rows)
  const int q    = w & 3;              // n-quarter
  const int row0 = blockIdx.x * RPB + rg * 4;

  float acc[32];
#pragma unroll
  for (int i = 0; i < 32; ++i) acc[i] = 0.0f;

#define CF(U, u)                                                              \
  {                                                                           \
    uint32_t pu = pv.U;                                                       \
    float br = __uint_as_float(pu << 16);                                     \
    float bi = __uint_as_float(pu & 0xFFFF0000u);                             \
    float4 A  = xa[u];                                                        \
    float4 Bx = xb[u];                                                        \
    float* a = acc + r * 8;                                                   \
    a[0] = fmaf(br, A.x, a[0]);  a[0] = fmaf(-bi, A.y, a[0]);                 \
    a[1] = fmaf(br, A.y, a[1]);  a[1] = fmaf(bi, A.x, a[1]);                  \
    a[2] = fmaf(br, A.z, a[2]);  a[2] = fmaf(-bi, A.w, a[2]);                 \
    a[3] = fmaf(br, A.w, a[3]);  a[3] = fmaf(bi, A.z, a[3]);                  \
    a[4] = fmaf(br, Bx.x, a[4]); a[4] = fmaf(-bi, Bx.y, a[4]);                \
    a[5] = fmaf(br, Bx.y, a[5]); a[5] = fmaf(bi, Bx.x, a[5]);                 \
    a[6] = fmaf(br, Bx.z, a[6]); a[6] = fmaf(-bi, Bx.w, a[6]);                \
    a[7] = fmaf(br, Bx.w, a[7]); a[7] = fmaf(bi, Bx.z, a[7]);                 \
  }

  if (PACKED) {
    const uint4* pr[4];
#pragma unroll
    for (int r = 0; r < 4; ++r)
      pr[r] = Bp + (size_t)(row0 + r) * 1024 + q * 256 + lane;   // uint4 units
    for (int i4 = 0; i4 < 4; ++i4) {
      const int nb = q * 1024 + i4 * 256 + lane;    // float4 index, component u at +u*64
      float4 xa[4], xb[4];
#pragma unroll
      for (int u = 0; u < 4; ++u) {
        xa[u] = reinterpret_cast<const float4*>(xl)[nb + u * 64];
        xb[u] = reinterpret_cast<const float4*>(xh)[nb + u * 64];
      }
#pragma unroll
      for (int r = 0; r < 4; ++r) {
        uint4 pv = pr[r][i4 * 64];
        CF(x, 0) CF(y, 1) CF(z, 2) CF(w, 3)
      }
    }
  } else {
    for (int i4 = 0; i4 < 4; ++i4) {
      const int nb = q * 1024 + i4 * 256 + lane;
      float4 xa[4], xb[4];
#pragma unroll
      for (int u = 0; u < 4; ++u) {
        xa[u] = reinterpret_cast<const float4*>(xl)[nb + u * 64];
        xb[u] = reinterpret_cast<const float4*>(xh)[nb + u * 64];
      }
#pragma unroll
      for (int r = 0; r < 4; ++r) {
        const float* brp = Brf + (size_t)(row0 + r) * NN + q * 1024 + i4 * 256 + lane;
        const float* bip = Bif + (size_t)(row0 + r) * NN + q * 1024 + i4 * 256 + lane;
        uint4 pv;
        pv.x = bf16rne(brp[0])   | (bf16rne(bip[0])   << 16);
        pv.y = bf16rne(brp[64])  | (bf16rne(bip[64])  << 16);
        pv.z = bf16rne(brp[128]) | (bf16rne(bip[128]) << 16);
        pv.w = bf16rne(brp[192]) | (bf16rne(bip[192]) << 16);
        CF(x, 0) CF(y, 1) CF(z, 2) CF(w, 3)
      }
    }
  }
#undef CF

  // ---- specialized halving butterfly: 32 vals over 64 lanes in 32 shfls ----
  // After level k (mask m=32>>k), lanes with bit(5-k) of lane select the upper half;
  // final: lane l holds fully-reduced v[j], j=(l>>1)&31, j = r*8+c.
#pragma unroll
  for (int k = 0; k < 5; ++k) {
    const int m    = 32 >> k;
    const int half = 16 >> k;
    const bool up  = (lane & m) != 0;
#pragma unroll
    for (int i = 0; i < half; ++i) {
      float send = up ? acc[i] : acc[i + half];
      float got  = __shfl_xor(send, m, 64);
      acc[i] = (up ? acc[i + half] : acc[i]) + got;
    }
  }
  {
    float v = acc[0] + __shfl_xor(acc[0], 1, 64);
    if (!(lane & 1)) red[w * 32 + ((lane >> 1) & 31)] = v;
  }
  __syncthreads();

  // ---- cross-wave (n-quarter) sum + diagonal term + writes ----
  if (tid < 128) {
    int rg2 = tid >> 5;
    int v   = tid & 31;
    float s = red[(rg2 * 4 + 0) * 32 + v] + red[(rg2 * 4 + 1) * 32 + v] +
              red[(rg2 * 4 + 2) * 32 + v] + red[(rg2 * 4 + 3) * 32 + v];
    int r  = v >> 3;
    int c  = v & 7;
    int b  = c >> 1;
    int ri = c & 1;
    int m  = blockIdx.x * RPB + rg2 * 4 + r;
    float om = omega[b * NN + m];
    const float* xs = (b < 2) ? xl : xh;
    float xr = xs[m * 4 + (b & 1) * 2];
    float xi = xs[m * 4 + (b & 1) * 2 + 1];
    // i*omega*(xr + i*xi) = -omega*xi + i*omega*xr
    s += (ri == 0) ? (-om * xi) : (om * xr);
    reinterpret_cast<float*>(stNext)[(b * NN + m) * 2 + ri] = s;
    if (ri == 0) outRe[b * NN + m] = s;      // d_out = REAL part only, [t][b][n]
  }
}

// ---------- host ----------
extern "C" void kernel_launch(void* const* d_in, const int* in_sizes, int n_in,
                              void* d_out, int out_size, void* d_ws, size_t ws_size,
                              hipStream_t stream) {
  const float* B_real = (const float*)d_in[0];
  const float* B_imag = (const float*)d_in[1];
  const float* omega  = (const float*)d_in[2];
  const float* ang    = (const float*)d_in[3];
  float* out = (float*)d_out;

  const int NT = out_size / (BB * NN);                           // 256
  const size_t packBytes = (size_t)NN * NN * sizeof(uint32_t);   // 67 MB
  const size_t stBytes   = (size_t)2 * BB * NN * sizeof(float2); // 256 KB
  const bool packed = ws_size >= packBytes + stBytes;

  uint4* Bp;
  float2* st;
  if (packed) {
    Bp = (uint4*)d_ws;
    st = (float2*)((char*)d_ws + packBytes);
  } else {
    Bp = nullptr;
    st = (float2*)d_ws;                                          // needs 256 KB
  }
  float2* st0 = st;
  float2* st1 = st + BB * NN;

  const size_t shmem = (size_t)(NN * 8 + 16 * 32) * sizeof(float);  // 133120 B
  (void)hipFuncSetAttribute((const void*)&step_kernel<true>,
                            hipFuncAttributeMaxDynamicSharedMemorySize, (int)shmem);
  (void)hipFuncSetAttribute((const void*)&step_kernel<false>,
                            hipFuncAttributeMaxDynamicSharedMemorySize, (int)shmem);

  if (packed) {
    pack_perm_kernel<<<NN * NN / 4 / 256, 256, 0, stream>>>(B_real, B_imag, Bp);
  }
  init_kernel<<<(BB * NN + 255) / 256, 256, 0, stream>>>(ang, st0, out);

  for (int t = 1; t < NT; ++t) {
    float2* sp = ((t - 1) & 1) ? st1 : st0;
    float2* sn = (t & 1) ? st1 : st0;
    float* outT = out + (size_t)t * BB * NN;
    if (packed) {
      step_kernel<true><<<NN / RPB, TPB, shmem, stream>>>(
          Bp, nullptr, nullptr, omega, sp, sn, outT);
    } else {
      step_kernel<false><<<NN / RPB, TPB, shmem, stream>>>(
          nullptr, B_real, B_imag, omega, sp, sn, outT);
    }
  }
}

// Round 6
// 5515.264 us; speedup vs baseline: 1.8608x; 1.8608x over previous
//
#include <hip/hip_runtime.h>
#include <stdint.h>

#define NN 4096
#define BB 4
#define RPB 16          // rows per block
#define TPB 1024

// ---------- bf16 round-to-nearest-even ----------
__device__ __forceinline__ uint32_t bf16rne(float f) {
  uint32_t u = __float_as_uint(f);
  return (u + 0x7FFFu + ((u >> 16) & 1u)) >> 16;
}

// ---------- straight pack (round-4): Bp[row*NN+c] = bf16(Br)|bf16(Bi)<<16 ----------
__global__ void pack_kernel(const float* __restrict__ Br, const float* __restrict__ Bi,
                            uint32_t* __restrict__ Bp) {
  int i = blockIdx.x * blockDim.x + threadIdx.x;   // over N*N/4
  float4 r = reinterpret_cast<const float4*>(Br)[i];
  float4 m = reinterpret_cast<const float4*>(Bi)[i];
  uint4 o;
  o.x = bf16rne(r.x) | (bf16rne(m.x) << 16);
  o.y = bf16rne(r.y) | (bf16rne(m.y) << 16);
  o.z = bf16rne(r.z) | (bf16rne(m.z) << 16);
  o.w = bf16rne(r.w) | (bf16rne(m.w) << 16);
  reinterpret_cast<uint4*>(Bp)[i] = o;
}

// ---------- x0 = exp(i*theta): state (complex interleaved) + out real plane t=0 ----------
__global__ void init_kernel(const float* __restrict__ ang,
                            float2* __restrict__ st0, float* __restrict__ out0) {
  int i = blockIdx.x * blockDim.x + threadIdx.x;
  if (i < BB * NN) {
    float s, c;
    sincosf(ang[i], &s, &c);
    st0[i] = make_float2(c, s);
    out0[i] = c;
  }
}

// ---------- one recurrence step ----------
// state [b][n] complex interleaved (float2); d_out gets REAL part only, [t][b][n]
// LDS x layout: logical float4 n = {r0,i0,r1,i1}(node n) stored at PHYSICAL index
// p(n) = n ^ ((n>>4)&3)  -- 2-bit XOR swizzle so the K-loop's per-lane 4-consecutive-
// float4 reads spread over all 32 banks (round-4 layout was ~32-way conflicted).
template <bool PACKED>
__global__ __launch_bounds__(TPB)
void step_kernel(const uint32_t* __restrict__ Bp,
                 const float* __restrict__ Brf,
                 const float* __restrict__ Bif,
                 const float* __restrict__ omega,
                 const float2* __restrict__ stPrev,
                 float2* __restrict__ stNext,
                 float* __restrict__ outRe) {
  extern __shared__ float lds[];
  float* xl  = lds;                // 4096 float4 = 64 KB (batches 0,1)
  float* xh  = lds + NN * 4;       // 64 KB (batches 2,3)
  float* red = lds + NN * 8;       // 2 KB

  const int tid = threadIdx.x;

  // ---- stage x_t into LDS: one swizzled b128 write per thread-iter ----
#pragma unroll
  for (int k = 0; k < 8; ++k) {
    int idx  = tid + k * TPB;            // 0..8191
    int half = idx >> 12;                // 0 -> xl, 1 -> xh
    int n    = idx & (NN - 1);
    float2 v0 = stPrev[(half * 2    ) * NN + n];
    float2 v1 = stPrev[(half * 2 + 1) * NN + n];
    float4 w4 = make_float4(v0.x, v0.y, v1.x, v1.y);
    int p = n ^ ((n >> 4) & 3);          // swizzled physical slot
    reinterpret_cast<float4*>(half ? xh : xl)[p] = w4;
  }
  __syncthreads();

  const int w    = tid >> 6;
  const int lane = tid & 63;
  const int rg   = w >> 2;             // row group (4 rows)
  const int q    = w & 3;              // n-quarter
  const int row0 = blockIdx.x * RPB + rg * 4;
  const int xk   = (lane >> 2) & 3;    // swizzle key for this lane's 4-float4 window

  float acc[4][8];
#pragma unroll
  for (int r = 0; r < 4; ++r)
#pragma unroll
    for (int c = 0; c < 8; ++c) acc[r][c] = 0.0f;

#define CFMA(A, BR, BI, XA, XB)                                   \
  A[0] = fmaf(BR, XA.x, A[0]); A[0] = fmaf(-BI, XA.y, A[0]);      \
  A[1] = fmaf(BR, XA.y, A[1]); A[1] = fmaf(BI, XA.x, A[1]);       \
  A[2] = fmaf(BR, XA.z, A[2]); A[2] = fmaf(-BI, XA.w, A[2]);      \
  A[3] = fmaf(BR, XA.w, A[3]); A[3] = fmaf(BI, XA.z, A[3]);       \
  A[4] = fmaf(BR, XB.x, A[4]); A[4] = fmaf(-BI, XB.y, A[4]);      \
  A[5] = fmaf(BR, XB.y, A[5]); A[5] = fmaf(BI, XB.x, A[5]);       \
  A[6] = fmaf(BR, XB.z, A[6]); A[6] = fmaf(-BI, XB.w, A[6]);      \
  A[7] = fmaf(BR, XB.w, A[7]); A[7] = fmaf(BI, XB.z, A[7]);

  if (PACKED) {
    const uint4* pr[4];
#pragma unroll
    for (int r = 0; r < 4; ++r)
      pr[r] = reinterpret_cast<const uint4*>(Bp + (size_t)(row0 + r) * NN + q * 1024);
#pragma unroll
    for (int i4 = 0; i4 < 4; ++i4) {
      const int n0 = q * 1024 + i4 * 256 + lane * 4;   // logical float4 idx (column group)
      float4 xa[4], xb[4];
#pragma unroll
      for (int j = 0; j < 4; ++j) {
        int p = n0 + (j ^ xk);           // physical slot of logical column n0+j
        xa[j] = reinterpret_cast<const float4*>(xl)[p];
        xb[j] = reinterpret_cast<const float4*>(xh)[p];
      }
#pragma unroll
      for (int r = 0; r < 4; ++r) {
        uint4 pv = pr[r][i4 * 64 + lane];
        float* a = acc[r];
        uint32_t u;
        u = pv.x; { float br = __uint_as_float(u << 16), bi = __uint_as_float(u & 0xFFFF0000u); CFMA(a, br, bi, xa[0], xb[0]); }
        u = pv.y; { float br = __uint_as_float(u << 16), bi = __uint_as_float(u & 0xFFFF0000u); CFMA(a, br, bi, xa[1], xb[1]); }
        u = pv.z; { float br = __uint_as_float(u << 16), bi = __uint_as_float(u & 0xFFFF0000u); CFMA(a, br, bi, xa[2], xb[2]); }
        u = pv.w; { float br = __uint_as_float(u << 16), bi = __uint_as_float(u & 0xFFFF0000u); CFMA(a, br, bi, xa[3], xb[3]); }
      }
    }
  } else {
    const float4* rr[4];
    const float4* ir[4];
#pragma unroll
    for (int r = 0; r < 4; ++r) {
      rr[r] = reinterpret_cast<const float4*>(Brf + (size_t)(row0 + r) * NN + q * 1024);
      ir[r] = reinterpret_cast<const float4*>(Bif + (size_t)(row0 + r) * NN + q * 1024);
    }
#pragma unroll
    for (int i4 = 0; i4 < 4; ++i4) {
      const int n0 = q * 1024 + i4 * 256 + lane * 4;
      float4 xa[4], xb[4];
#pragma unroll
      for (int j = 0; j < 4; ++j) {
        int p = n0 + (j ^ xk);
        xa[j] = reinterpret_cast<const float4*>(xl)[p];
        xb[j] = reinterpret_cast<const float4*>(xh)[p];
      }
#pragma unroll
      for (int r = 0; r < 4; ++r) {
        float4 pvr = rr[r][i4 * 64 + lane];
        float4 pvi = ir[r][i4 * 64 + lane];
        float* a = acc[r];
        CFMA(a, pvr.x, pvi.x, xa[0], xb[0]);
        CFMA(a, pvr.y, pvi.y, xa[1], xb[1]);
        CFMA(a, pvr.z, pvi.z, xa[2], xb[2]);
        CFMA(a, pvr.w, pvi.w, xa[3], xb[3]);
      }
    }
  }
#undef CFMA

  // ---- in-wave butterfly reduction over 64 lanes (round-4 form) ----
#pragma unroll
  for (int r = 0; r < 4; ++r) {
#pragma unroll
    for (int c = 0; c < 8; ++c) {
      float v = acc[r][c];
      v += __shfl_xor(v, 32, 64);
      v += __shfl_xor(v, 16, 64);
      v += __shfl_xor(v, 8, 64);
      v += __shfl_xor(v, 4, 64);
      v += __shfl_xor(v, 2, 64);
      v += __shfl_xor(v, 1, 64);
      acc[r][c] = v;
    }
  }
  if (lane == 0) {
#pragma unroll
    for (int r = 0; r < 4; ++r)
#pragma unroll
      for (int c = 0; c < 8; ++c) red[w * 32 + r * 8 + c] = acc[r][c];
  }
  __syncthreads();

  // ---- cross-wave sum + diagonal term + writes ----
  if (tid < 128) {
    int rg2 = tid >> 5;
    int v   = tid & 31;
    float s = red[(rg2 * 4 + 0) * 32 + v] + red[(rg2 * 4 + 1) * 32 + v] +
              red[(rg2 * 4 + 2) * 32 + v] + red[(rg2 * 4 + 3) * 32 + v];
    int r  = v >> 3;
    int c  = v & 7;
    int b  = c >> 1;
    int ri = c & 1;
    int m  = blockIdx.x * RPB + rg2 * 4 + r;
    float om = omega[b * NN + m];
    const float* xs = (b < 2) ? xl : xh;
    int mp = m ^ ((m >> 4) & 3);         // swizzled physical slot of node m
    float xr = xs[mp * 4 + (b & 1) * 2];
    float xi = xs[mp * 4 + (b & 1) * 2 + 1];
    // i*omega*(xr + i*xi) = -omega*xi + i*omega*xr
    s += (ri == 0) ? (-om * xi) : (om * xr);
    reinterpret_cast<float*>(stNext)[(b * NN + m) * 2 + ri] = s;
    if (ri == 0) outRe[b * NN + m] = s;  // d_out = REAL part only, [t][b][n]
  }
}

// ---------- host ----------
extern "C" void kernel_launch(void* const* d_in, const int* in_sizes, int n_in,
                              void* d_out, int out_size, void* d_ws, size_t ws_size,
                              hipStream_t stream) {
  const float* B_real = (const float*)d_in[0];
  const float* B_imag = (const float*)d_in[1];
  const float* omega  = (const float*)d_in[2];
  const float* ang    = (const float*)d_in[3];
  float* out = (float*)d_out;

  const int NT = out_size / (BB * NN);                           // 256
  const size_t packBytes = (size_t)NN * NN * sizeof(uint32_t);   // 67 MB
  const size_t stBytes   = (size_t)2 * BB * NN * sizeof(float2); // 256 KB
  const bool packed = ws_size >= packBytes + stBytes;

  uint32_t* Bp;
  float2* st;
  if (packed) {
    Bp = (uint32_t*)d_ws;
    st = (float2*)((char*)d_ws + packBytes);
  } else {
    Bp = nullptr;
    st = (float2*)d_ws;                                          // needs 256 KB
  }
  float2* st0 = st;
  float2* st1 = st + BB * NN;

  const size_t shmem = (size_t)(NN * 8 + 16 * 32) * sizeof(float);  // 133120 B
  (void)hipFuncSetAttribute((const void*)&step_kernel<true>,
                            hipFuncAttributeMaxDynamicSharedMemorySize, (int)shmem);
  (void)hipFuncSetAttribute((const void*)&step_kernel<false>,
                            hipFuncAttributeMaxDynamicSharedMemorySize, (int)shmem);

  if (packed) {
    pack_kernel<<<NN * NN / 4 / 256, 256, 0, stream>>>(B_real, B_imag, Bp);
  }
  init_kernel<<<(BB * NN + 255) / 256, 256, 0, stream>>>(ang, st0, out);

  for (int t = 1; t < NT; ++t) {
    float2* sp = ((t - 1) & 1) ? st1 : st0;
    float2* sn = (t & 1) ? st1 : st0;
    float* outT = out + (size_t)t * BB * NN;
    if (packed) {
      step_kernel<true><<<NN / RPB, TPB, shmem, stream>>>(
          Bp, nullptr, nullptr, omega, sp, sn, outT);
    } else {
      step_kernel<false><<<NN / RPB, TPB, shmem, stream>>>(
          nullptr, B_real, B_imag, omega, sp, sn, outT);
    }
  }
}